// Round 1
// baseline (948.013 us; speedup 1.0000x reference)
//
#include <hip/hip_runtime.h>
#include <cmath>

// SDYUnit: per-pixel 1x1-conv chain + pixel shuffle + tanh.
// N=24 independent 192x192 channels, valid region 190x190.
// Layers: taps(4) ->64 relu, 4x(64->64 relu), 64->16, shuffle r=4, tanh.

static constexpr int Hh = 190, Ww = 190, Him = 192, Wim = 192, Nimg = 24;
static constexpr int NPIX = Nimg * Hh * Ww;          // 866,400
static constexpr int WS_W1 = 0;                      // [4][64]
static constexpr int WS_WM = 256;                    // 4 x [64][64]
static constexpr int WS_W6 = 256 + 4 * 4096;         // [64][16]

// Transpose weights to [k][g] layout so the main kernel's per-k weight rows
// are contiguous -> s_load_dwordx16 scalar loads (thread-uniform addresses).
__global__ __launch_bounds__(256) void prep_kernel(
    const float* __restrict__ W1, const float* __restrict__ W2,
    const float* __restrict__ W3, const float* __restrict__ W4,
    const float* __restrict__ W5, const float* __restrict__ W6,
    float* __restrict__ ws) {
  int t = threadIdx.x + blockIdx.x * blockDim.x;
  if (t < 256) {               // W1: (64,4) -> W1t[k][g]
    int k = t >> 6, g = t & 63;
    ws[WS_W1 + t] = W1[g * 4 + k];
  }
  if (t < 4096) {              // W2..W5: (64,64) -> Wt[k][g]
    int k = t >> 6, g = t & 63;
    ws[WS_WM + 0 * 4096 + t] = W2[g * 64 + k];
    ws[WS_WM + 1 * 4096 + t] = W3[g * 64 + k];
    ws[WS_WM + 2 * 4096 + t] = W4[g * 64 + k];
    ws[WS_WM + 3 * 4096 + t] = W5[g * 64 + k];
  }
  if (t < 1024) {              // W6: (16,64) -> W6t[k][o]
    int k = t >> 4, o = t & 15;
    ws[WS_W6 + t] = W6[o * 64 + k];
  }
}

__global__ __launch_bounds__(256) void fused_kernel(
    const float* __restrict__ x, const float* __restrict__ ws,
    const float* __restrict__ b1, const float* __restrict__ b2,
    const float* __restrict__ b3, const float* __restrict__ b4,
    const float* __restrict__ b5, const float* __restrict__ b6,
    float* __restrict__ out) {
  int t = blockIdx.x * 256 + threadIdx.x;
  if (t >= NPIX) return;

  int j = t % Ww;
  int rem = t / Ww;
  int i = rem % Hh;
  int n = rem / Hh;

  // 4 taps of the 2x2 window
  const float* xp = x + (n * Him + i) * Wim + j;
  float tap0 = xp[0];
  float tap1 = xp[1];
  float tap2 = xp[Wim];
  float tap3 = xp[Wim + 1];

  float f0[64], f1[64];

  // conv1: 4 -> 64, relu
  {
    const float* w = ws + WS_W1;  // [4][64]
#pragma unroll
    for (int g = 0; g < 64; ++g) f0[g] = b1[g];
#pragma unroll
    for (int g = 0; g < 64; ++g) f0[g] = fmaf(w[0 * 64 + g], tap0, f0[g]);
#pragma unroll
    for (int g = 0; g < 64; ++g) f0[g] = fmaf(w[1 * 64 + g], tap1, f0[g]);
#pragma unroll
    for (int g = 0; g < 64; ++g) f0[g] = fmaf(w[2 * 64 + g], tap2, f0[g]);
#pragma unroll
    for (int g = 0; g < 64; ++g) f0[g] = fmaf(w[3 * 64 + g], tap3, f0[g]);
#pragma unroll
    for (int g = 0; g < 64; ++g) f0[g] = fmaxf(f0[g], 0.0f);
  }

  // conv2..conv5: 64 -> 64, relu.  Rolled over L to keep code in I-cache;
  // inner 64x64 fully unrolled so all register indices are static (rule #20).
#pragma unroll 1
  for (int L = 0; L < 4; ++L) {
    const float* w = ws + WS_WM + L * 4096;  // [64][64] (k-major)
    const float* bb = (L == 0) ? b2 : (L == 1) ? b3 : (L == 2) ? b4 : b5;
#pragma unroll
    for (int g = 0; g < 64; ++g) f1[g] = bb[g];
#pragma unroll
    for (int k = 0; k < 64; ++k) {
      float a = f0[k];
#pragma unroll
      for (int g = 0; g < 64; ++g) f1[g] = fmaf(w[k * 64 + g], a, f1[g]);
    }
#pragma unroll
    for (int g = 0; g < 64; ++g) f0[g] = fmaxf(f1[g], 0.0f);
  }

  // conv6: 64 -> 16 (no act)
  float y[16];
  {
    const float* w = ws + WS_W6;  // [64][16]
#pragma unroll
    for (int o = 0; o < 16; ++o) y[o] = b6[o];
#pragma unroll
    for (int k = 0; k < 64; ++k) {
      float a = f0[k];
#pragma unroll
      for (int o = 0; o < 16; ++o) y[o] = fmaf(w[k * 16 + o], a, y[o]);
    }
  }

  // pixel shuffle (r=4) + tanh; coalesced float4 stores (760 = 4*190).
  float* op = out + ((size_t)(n * 760 + i * 4)) * 760 + j * 4;
#pragma unroll
  for (int di = 0; di < 4; ++di) {
    float4 v;
    v.x = tanhf(y[di * 4 + 0]);
    v.y = tanhf(y[di * 4 + 1]);
    v.z = tanhf(y[di * 4 + 2]);
    v.w = tanhf(y[di * 4 + 3]);
    *reinterpret_cast<float4*>(op + (size_t)di * 760) = v;
  }
}

extern "C" void kernel_launch(void* const* d_in, const int* in_sizes, int n_in,
                              void* d_out, int out_size, void* d_ws, size_t ws_size,
                              hipStream_t stream) {
  const float* x  = (const float*)d_in[0];
  const float* W1 = (const float*)d_in[1];
  const float* b1 = (const float*)d_in[2];
  const float* W2 = (const float*)d_in[3];
  const float* b2 = (const float*)d_in[4];
  const float* W3 = (const float*)d_in[5];
  const float* b3 = (const float*)d_in[6];
  const float* W4 = (const float*)d_in[7];
  const float* b4 = (const float*)d_in[8];
  const float* W5 = (const float*)d_in[9];
  const float* b5 = (const float*)d_in[10];
  const float* W6 = (const float*)d_in[11];
  const float* b6 = (const float*)d_in[12];

  float* ws = (float*)d_ws;
  hipLaunchKernelGGL(prep_kernel, dim3(16), dim3(256), 0, stream,
                     W1, W2, W3, W4, W5, W6, ws);

  int blocks = (NPIX + 255) / 256;
  hipLaunchKernelGGL(fused_kernel, dim3(blocks), dim3(256), 0, stream,
                     x, ws, b1, b2, b3, b4, b5, b6, (float*)d_out);
}

// Round 2
// 124.568 us; speedup vs baseline: 7.6104x; 7.6104x over previous
//
#include <hip/hip_runtime.h>
#include <cmath>

// SDYUnit via split-bf16 MFMA: per-pixel 1x1-conv chain, fp32 emulated as
// hi*hi + hi*lo + lo*hi in mfma_f32_16x16x32_bf16 (f32 accum).
// Workgroup = 256 pixels = 4 waves x 64 pixels; each wave has a private
// 16KB LDS activation region (hi+lo planes), XOR-swizzled; no barriers.

static constexpr int Hh = 190, Ww = 190, Him = 192, Wim = 192, Nimg = 24;
static constexpr int NPIX = Nimg * Hh * Ww;        // 866,400
static constexpr int NWG  = (NPIX + 255) / 256;    // 3385

typedef __attribute__((ext_vector_type(8))) short short8v;  // bf16 frag (4 VGPR)
typedef __attribute__((ext_vector_type(4))) float f32x4;    // C/D frag
typedef __attribute__((ext_vector_type(2))) unsigned int uint2v;

// ws layout (in shorts unless noted):
//   mid-layer A frags (weights W[out][in], M=K=64): 4L x 4mt x 2ks x 64lane x 8
static constexpr int WHI_MID = 0;          // 32 frags * 512 shorts
static constexpr int WLO_MID = 16384;
static constexpr int W6HI    = 32768;      // 2 frags * 512
static constexpr int W6LO    = 33792;
static constexpr int W1T_BYTE = 34816 * 2; // then 256 floats: W1t[k][g]

__device__ __forceinline__ unsigned short bf16_rne(float f) {
  unsigned u = __builtin_bit_cast(unsigned, f);
  unsigned r = u + 0x7FFFu + ((u >> 16) & 1u);
  return (unsigned short)(r >> 16);
}

__global__ __launch_bounds__(256) void prep_kernel(
    const float* __restrict__ W1, const float* __restrict__ W2,
    const float* __restrict__ W3, const float* __restrict__ W4,
    const float* __restrict__ W5, const float* __restrict__ W6,
    void* __restrict__ wsv) {
  short* wsS = (short*)wsv;
  float* w1t = (float*)((char*)wsv + W1T_BYTE);
  int t0 = blockIdx.x * 256 + threadIdx.x;
  int stride = gridDim.x * 256;
  // mid-layer weight fragments, hi/lo split (RNE both)
  for (int idx = t0; idx < 32 * 512; idx += stride) {
    int j = idx & 7, lane = (idx >> 3) & 63, fi = idx >> 9;
    int ks = fi & 1, mt = (fi >> 1) & 3, L = fi >> 3;
    const float* W = (L == 0) ? W2 : (L == 1) ? W3 : (L == 2) ? W4 : W5;
    int row = mt * 16 + (lane & 15);
    int k = ks * 32 + (lane >> 4) * 8 + j;
    float w = W[row * 64 + k];
    unsigned short h = bf16_rne(w);
    float hf = __builtin_bit_cast(float, (unsigned)h << 16);
    wsS[WHI_MID + idx] = (short)h;
    wsS[WLO_MID + idx] = (short)bf16_rne(w - hf);
  }
  // W6 fragments (M=16)
  for (int idx = t0; idx < 2 * 512; idx += stride) {
    int j = idx & 7, lane = (idx >> 3) & 63, ks = idx >> 9;
    int row = lane & 15;
    int k = ks * 32 + (lane >> 4) * 8 + j;
    float w = W6[row * 64 + k];
    unsigned short h = bf16_rne(w);
    float hf = __builtin_bit_cast(float, (unsigned)h << 16);
    wsS[W6HI + idx] = (short)h;
    wsS[W6LO + idx] = (short)bf16_rne(w - hf);
  }
  // W1 transposed, f32 (layer 1 stays VALU)
  for (int idx = t0; idx < 256; idx += stride) {
    int k = idx >> 6, g = idx & 63;
    w1t[idx] = W1[g * 4 + k];
  }
}

__device__ __forceinline__ f32x4 zero4() {
  f32x4 z = {0.f, 0.f, 0.f, 0.f};
  return z;
}

__global__ __launch_bounds__(256, 2) void fused_kernel(
    const float* __restrict__ x, const void* __restrict__ wsv,
    const float* __restrict__ b1, const float* __restrict__ b2,
    const float* __restrict__ b3, const float* __restrict__ b4,
    const float* __restrict__ b5, const float* __restrict__ b6,
    float* __restrict__ out) {
  __shared__ short act_hi[4][4096];  // [wave][pix(64) x feat(64)], swizzled
  __shared__ short act_lo[4][4096];
  const short* wsS = (const short*)wsv;
  const float* w1t = (const float*)((const char*)wsv + W1T_BYTE);

  int tid = threadIdx.x;
  int wave = tid >> 6, q = tid & 63;
  char* AH = (char*)(&act_hi[wave][0]);
  char* AL = (char*)(&act_lo[wave][0]);
  int wgbase = blockIdx.x * 256;

  // ---------- layer 1: 4 -> 64, relu (f32 VALU), split to LDS ----------
  {
    int p = wgbase + tid;
    int pc = p < NPIX ? p : NPIX - 1;
    int jj = pc % Ww; int r2 = pc / Ww; int ii = r2 % Hh; int nn = r2 / Hh;
    const float* xp = x + (nn * Him + ii) * Wim + jj;
    float t0 = xp[0], t1 = xp[1], t2 = xp[Wim], t3 = xp[Wim + 1];
    float f[64];
#pragma unroll
    for (int g = 0; g < 64; ++g)
      f[g] = fmaxf(fmaf(w1t[g], t0, fmaf(w1t[64 + g], t1,
                   fmaf(w1t[128 + g], t2, fmaf(w1t[192 + g], t3, b1[g])))), 0.f);
    int swz = (q & 7) << 4;
#pragma unroll
    for (int fb = 0; fb < 8; ++fb) {
      short8v hv, lv;
#pragma unroll
      for (int e = 0; e < 8; ++e) {
        float v = f[fb * 8 + e];
        unsigned u = __builtin_bit_cast(unsigned, v);
        float hf = __builtin_bit_cast(float, u & 0xFFFF0000u);
        hv[e] = (short)(unsigned short)(u >> 16);   // trunc hi
        lv[e] = (short)bf16_rne(v - hf);            // rne lo
      }
      int off = q * 128 + ((fb * 16) ^ swz);
      *(short8v*)(AH + off) = hv;
      *(short8v*)(AL + off) = lv;
    }
  }
  asm volatile("s_waitcnt lgkmcnt(0)" ::: "memory");

  // ---------- layers 2..5: 64 -> 64, relu, MFMA split-bf16 ----------
#pragma unroll 1
  for (int L = 0; L < 4; ++L) {
    const float* bb = (L == 0) ? b2 : (L == 1) ? b3 : (L == 2) ? b4 : b5;
    short8v bh[2][4], bl[2][4];
#pragma unroll
    for (int ks = 0; ks < 2; ++ks)
#pragma unroll
      for (int nt = 0; nt < 4; ++nt) {
        int pix = nt * 16 + (q & 15);
        int kb2 = ks * 64 + (q >> 4) * 16;
        int off = pix * 128 + (kb2 ^ ((pix & 7) << 4));
        bh[ks][nt] = *(const short8v*)(AH + off);
        bl[ks][nt] = *(const short8v*)(AL + off);
      }
    f32x4 acc[4][4];
#pragma unroll
    for (int mt = 0; mt < 4; ++mt)
#pragma unroll
      for (int nt = 0; nt < 4; ++nt) acc[mt][nt] = zero4();
#pragma unroll
    for (int mt = 0; mt < 4; ++mt) {
#pragma unroll
      for (int ks = 0; ks < 2; ++ks) {
        int fi = ((L * 4 + mt) * 2 + ks) * 512 + q * 8;
        short8v ah = *(const short8v*)(wsS + WHI_MID + fi);
        short8v al = *(const short8v*)(wsS + WLO_MID + fi);
#pragma unroll
        for (int nt = 0; nt < 4; ++nt) {
          acc[mt][nt] = __builtin_amdgcn_mfma_f32_16x16x32_bf16(ah, bh[ks][nt], acc[mt][nt], 0, 0, 0);
          acc[mt][nt] = __builtin_amdgcn_mfma_f32_16x16x32_bf16(ah, bl[ks][nt], acc[mt][nt], 0, 0, 0);
          acc[mt][nt] = __builtin_amdgcn_mfma_f32_16x16x32_bf16(al, bh[ks][nt], acc[mt][nt], 0, 0, 0);
        }
      }
    }
    // bias + relu + split + write back (in-place, same wave region only)
#pragma unroll
    for (int mt = 0; mt < 4; ++mt) {
      f32x4 bv = *(const f32x4*)(bb + mt * 16 + (q >> 4) * 4);
#pragma unroll
      for (int nt = 0; nt < 4; ++nt) {
        f32x4 v = acc[mt][nt] + bv;
        int pix = nt * 16 + (q & 15);
        int fb2 = (mt * 16 + (q >> 4) * 4) * 2;  // byte offset of 4 feats
        int off = pix * 128 + (fb2 ^ ((pix & 7) << 4));
        unsigned hpack[2], lpack[2];
#pragma unroll
        for (int e2 = 0; e2 < 2; ++e2) {
          float v0 = fmaxf(v[2 * e2], 0.f), v1 = fmaxf(v[2 * e2 + 1], 0.f);
          unsigned u0 = __builtin_bit_cast(unsigned, v0);
          unsigned u1 = __builtin_bit_cast(unsigned, v1);
          float hf0 = __builtin_bit_cast(float, u0 & 0xFFFF0000u);
          float hf1 = __builtin_bit_cast(float, u1 & 0xFFFF0000u);
          hpack[e2] = (u0 >> 16) | (u1 & 0xFFFF0000u);
          lpack[e2] = (unsigned)bf16_rne(v0 - hf0) | ((unsigned)bf16_rne(v1 - hf1) << 16);
        }
        uint2v hq = {hpack[0], hpack[1]}, lq = {lpack[0], lpack[1]};
        *(uint2v*)(AH + off) = hq;
        *(uint2v*)(AL + off) = lq;
      }
    }
    asm volatile("s_waitcnt lgkmcnt(0)" ::: "memory");
  }

  // ---------- layer 6: 64 -> 16 (no act), tanh, pixel-shuffle store ----------
  {
    short8v bh[2][4], bl[2][4];
#pragma unroll
    for (int ks = 0; ks < 2; ++ks)
#pragma unroll
      for (int nt = 0; nt < 4; ++nt) {
        int pix = nt * 16 + (q & 15);
        int kb2 = ks * 64 + (q >> 4) * 16;
        int off = pix * 128 + (kb2 ^ ((pix & 7) << 4));
        bh[ks][nt] = *(const short8v*)(AH + off);
        bl[ks][nt] = *(const short8v*)(AL + off);
      }
    f32x4 acc6[4];
#pragma unroll
    for (int nt = 0; nt < 4; ++nt) acc6[nt] = zero4();
#pragma unroll
    for (int ks = 0; ks < 2; ++ks) {
      int fi = ks * 512 + q * 8;
      short8v ah = *(const short8v*)(wsS + W6HI + fi);
      short8v al = *(const short8v*)(wsS + W6LO + fi);
#pragma unroll
      for (int nt = 0; nt < 4; ++nt) {
        acc6[nt] = __builtin_amdgcn_mfma_f32_16x16x32_bf16(ah, bh[ks][nt], acc6[nt], 0, 0, 0);
        acc6[nt] = __builtin_amdgcn_mfma_f32_16x16x32_bf16(ah, bl[ks][nt], acc6[nt], 0, 0, 0);
        acc6[nt] = __builtin_amdgcn_mfma_f32_16x16x32_bf16(al, bh[ks][nt], acc6[nt], 0, 0, 0);
      }
    }
    f32x4 b6v = *(const f32x4*)(b6 + (q >> 4) * 4);
#pragma unroll
    for (int nt = 0; nt < 4; ++nt) {
      f32x4 v = acc6[nt] + b6v;
      int pix = nt * 16 + (q & 15);
      int p2 = wgbase + wave * 64 + pix;
      if (p2 < NPIX) {
        int jj = p2 % Ww; int r2 = p2 / Ww; int ii = r2 % Hh; int nn = r2 / Hh;
        float4 st;
        st.x = tanhf(v[0]); st.y = tanhf(v[1]);
        st.z = tanhf(v[2]); st.w = tanhf(v[3]);
        size_t o = ((size_t)(nn * 760 + ii * 4 + (q >> 4)) * 760) + (size_t)jj * 4;
        *reinterpret_cast<float4*>(out + o) = st;
      }
    }
  }
}

extern "C" void kernel_launch(void* const* d_in, const int* in_sizes, int n_in,
                              void* d_out, int out_size, void* d_ws, size_t ws_size,
                              hipStream_t stream) {
  const float* x  = (const float*)d_in[0];
  const float* W1 = (const float*)d_in[1];
  const float* b1 = (const float*)d_in[2];
  const float* W2 = (const float*)d_in[3];
  const float* b2 = (const float*)d_in[4];
  const float* W3 = (const float*)d_in[5];
  const float* b3 = (const float*)d_in[6];
  const float* W4 = (const float*)d_in[7];
  const float* b4 = (const float*)d_in[8];
  const float* W5 = (const float*)d_in[9];
  const float* b5 = (const float*)d_in[10];
  const float* W6 = (const float*)d_in[11];
  const float* b6 = (const float*)d_in[12];

  hipLaunchKernelGGL(prep_kernel, dim3(16), dim3(256), 0, stream,
                     W1, W2, W3, W4, W5, W6, d_ws);
  hipLaunchKernelGGL(fused_kernel, dim3(NWG), dim3(256), 0, stream,
                     x, d_ws, b1, b2, b3, b4, b5, b6, (float*)d_out);
}